// Round 1
// baseline (202.274 us; speedup 1.0000x reference)
//
#include <hip/hip_runtime.h>
#include <math.h>

// Problem constants (match reference).
#define BDIM 4096
#define TDIM 2048

// gamma powers as exact compile-time folded constants
constexpr double gpow(int e) {
    double r = 1.0;
    for (int i = 0; i < e; ++i) r *= 0.99;
    return r;
}

__device__ __forceinline__ float logsig(float x) {
    // log(sigmoid(x)) = min(x,0) - log1p(exp(-|x|))  (matches jax.nn.log_sigmoid)
    return fminf(x, 0.0f) - log1pf(expf(-fabsf(x)));
}

// K1: per-row reverse discounted scan (c[t] = wr[t] + g*c[t+1]), write cum,
// accumulate per-block column partial sums of (cum - baseline).
// Restructured: rows_per_block runtime (4 preferred -> 1024 blocks = 4 blocks/CU),
// single barrier per row (double-buffered wsum), software prefetch of next row.
__global__ __launch_bounds__(256, 4) void k1_scan(
    const float* __restrict__ logits,
    const float* __restrict__ weight,
    const float* __restrict__ baselines,
    float* __restrict__ cum_out,
    float* __restrict__ partial,
    int rows_per_block)
{
    const int tid  = threadIdx.x;
    const int lane = tid & 63;
    const int wave = tid >> 6;
    const int t0   = tid * 8;          // 8 contiguous elements per thread

    const float G    = 0.99f;
    const float G8   = (float)gpow(8);
    const float G512 = (float)gpow(512);
    const float LOG2G = -0.014499569695115089f;  // log2(0.99)
    // gamma^(8-k) for k=0..7
    const float gk[8] = {(float)gpow(8), (float)gpow(7), (float)gpow(6), (float)gpow(5),
                         (float)gpow(4), (float)gpow(3), (float)gpow(2), (float)gpow(1)};

    // lane-constant: gamma^((64-lane)*8), hoisted off the per-row critical chain
    const float lane_pow = exp2f((float)((64 - lane) * 8) * LOG2G);

    __shared__ float wsum[2][4];

    float colacc[8];
#pragma unroll
    for (int k = 0; k < 8; ++k) colacc[k] = 0.0f;

    const int row0 = blockIdx.x * rows_per_block;
    size_t base = (size_t)row0 * TDIM + t0;

    // preload row 0
    float4 x0 = *reinterpret_cast<const float4*>(logits + base);
    float4 x1 = *reinterpret_cast<const float4*>(logits + base + 4);
    float4 w0 = *reinterpret_cast<const float4*>(weight + base);
    float4 w1 = *reinterpret_cast<const float4*>(weight + base + 4);
    float4 b0 = *reinterpret_cast<const float4*>(baselines + base);
    float4 b1 = *reinterpret_cast<const float4*>(baselines + base + 4);

    for (int r = 0; r < rows_per_block; ++r) {
        const size_t nbase = base + TDIM;
        const bool has_next = (r + 1 < rows_per_block);

        float wr[8];
        wr[0] = w0.x * logsig(x0.x); wr[1] = w0.y * logsig(x0.y);
        wr[2] = w0.z * logsig(x0.z); wr[3] = w0.w * logsig(x0.w);
        wr[4] = w1.x * logsig(x1.x); wr[5] = w1.y * logsig(x1.y);
        wr[6] = w1.z * logsig(x1.z); wr[7] = w1.w * logsig(x1.w);

        // prefetch next row NOW — latency hides under the scan chain below
        float4 nx0, nx1, nw0, nw1, nb0, nb1;
        if (has_next) {
            nx0 = *reinterpret_cast<const float4*>(logits + nbase);
            nx1 = *reinterpret_cast<const float4*>(logits + nbase + 4);
            nw0 = *reinterpret_cast<const float4*>(weight + nbase);
            nw1 = *reinterpret_cast<const float4*>(weight + nbase + 4);
            nb0 = *reinterpret_cast<const float4*>(baselines + nbase);
            nb1 = *reinterpret_cast<const float4*>(baselines + nbase + 4);
        }

        // local suffix scan: loc[k] = sum_{s>=k} g^(s-k) wr[s]
        float loc[8];
        loc[7] = wr[7];
#pragma unroll
        for (int k = 6; k >= 0; --k) loc[k] = fmaf(G, loc[k + 1], wr[k]);

        // wave-level weighted suffix scan over per-thread totals, factor g^8
        float v = loc[0];
        float f = G8;
#pragma unroll
        for (int o = 1; o < 64; o <<= 1) {
            float up = __shfl_down(v, (unsigned)o, 64);
            if (lane + o < 64) v = fmaf(f, up, v);
            f *= f;
        }

        // cross-wave carry via LDS — ONE barrier per row (double-buffered)
        const int buf = r & 1;
        if (lane == 0) wsum[buf][wave] = v;
        __syncthreads();
        const float W1 = wsum[buf][1], W2 = wsum[buf][2], W3 = wsum[buf][3];
        const float FC3 = W3;
        const float FC2 = fmaf(G512, FC3, W2);
        const float FC1 = fmaf(G512, FC2, W1);
        const float carry = (wave == 0) ? FC1 : (wave == 1) ? FC2 : (wave == 2) ? FC3 : 0.0f;

        // full suffix value at this thread's first element
        const float vfull = fmaf(lane_pow, carry, v);
        // cumulative at element t0+8 (tail): next lane's vfull; lane 63 -> carry
        const float vn = __shfl_down(vfull, 1, 64);
        const float tail = (lane == 63) ? carry : vn;

        float c[8];
#pragma unroll
        for (int k = 0; k < 8; ++k) c[k] = fmaf(gk[k], tail, loc[k]);

        *reinterpret_cast<float4*>(cum_out + base)     = make_float4(c[0], c[1], c[2], c[3]);
        *reinterpret_cast<float4*>(cum_out + base + 4) = make_float4(c[4], c[5], c[6], c[7]);

        colacc[0] += c[0] - b0.x; colacc[1] += c[1] - b0.y;
        colacc[2] += c[2] - b0.z; colacc[3] += c[3] - b0.w;
        colacc[4] += c[4] - b1.x; colacc[5] += c[5] - b1.y;
        colacc[6] += c[6] - b1.z; colacc[7] += c[7] - b1.w;

        base = nbase;
        if (has_next) {
            x0 = nx0; x1 = nx1; w0 = nw0; w1 = nw1; b0 = nb0; b1 = nb1;
        }
    }

    const size_t pbase = (size_t)blockIdx.x * TDIM + t0;
    *reinterpret_cast<float4*>(partial + pbase)     = make_float4(colacc[0], colacc[1], colacc[2], colacc[3]);
    *reinterpret_cast<float4*>(partial + pbase + 4) = make_float4(colacc[4], colacc[5], colacc[6], colacc[7]);
}

// K2: reduce P partial rows per column into colsum (32 slices, atomics: 32/col).
__global__ __launch_bounds__(256) void k2_colsum(
    const float* __restrict__ partial, float* __restrict__ colsum, int rows_per_slice)
{
    const int gid   = blockIdx.x * 256 + threadIdx.x;   // 0..65535
    const int col   = gid & (TDIM - 1);
    const int slice = gid >> 11;                        // 0..31
    const float* p = partial + (size_t)slice * rows_per_slice * TDIM + col;
    float s = 0.0f;
#pragma unroll 8
    for (int i = 0; i < rows_per_slice; ++i) s += p[(size_t)i * TDIM];
    atomicAdd(colsum + col, s);
}

// K3: objective[t] = sum_b clip(cum - baseline - mean, +-5) * log_probs
// float4 across columns, 16 rows/thread, grid (2,256) = 512 blocks = 8 waves/CU.
#define K3_ROWS 16
__global__ __launch_bounds__(256) void k3_obj(
    const float* __restrict__ cum,
    const float* __restrict__ baselines,
    const float* __restrict__ lp,
    const float* __restrict__ colsum,
    float* __restrict__ obj)
{
    const int c4 = (blockIdx.x * 256 + threadIdx.x) * 4;   // column group
    const int r0 = blockIdx.y * K3_ROWS;
    const float inv = 1.0f / (float)BDIM;
    float4 ms = *reinterpret_cast<const float4*>(colsum + c4);
    const float m0 = ms.x * inv, m1 = ms.y * inv, m2 = ms.z * inv, m3 = ms.w * inv;

    float a0 = 0.0f, a1 = 0.0f, a2 = 0.0f, a3 = 0.0f;
    size_t idx = (size_t)r0 * TDIM + c4;
#pragma unroll 4
    for (int r = 0; r < K3_ROWS; ++r, idx += TDIM) {
        float4 c = *reinterpret_cast<const float4*>(cum + idx);
        float4 b = *reinterpret_cast<const float4*>(baselines + idx);
        float4 l = *reinterpret_cast<const float4*>(lp + idx);
        float v0 = fminf(fmaxf(c.x - b.x - m0, -5.0f), 5.0f);
        float v1 = fminf(fmaxf(c.y - b.y - m1, -5.0f), 5.0f);
        float v2 = fminf(fmaxf(c.z - b.z - m2, -5.0f), 5.0f);
        float v3 = fminf(fmaxf(c.w - b.w - m3, -5.0f), 5.0f);
        a0 = fmaf(v0, l.x, a0);
        a1 = fmaf(v1, l.y, a1);
        a2 = fmaf(v2, l.z, a2);
        a3 = fmaf(v3, l.w, a3);
    }
    atomicAdd(obj + c4 + 0, a0);
    atomicAdd(obj + c4 + 1, a1);
    atomicAdd(obj + c4 + 2, a2);
    atomicAdd(obj + c4 + 3, a3);
}

extern "C" void kernel_launch(void* const* d_in, const int* in_sizes, int n_in,
                              void* d_out, int out_size, void* d_ws, size_t ws_size,
                              hipStream_t stream) {
    const float* log_probs = (const float*)d_in[0];   // [B,T]
    const float* logits    = (const float*)d_in[1];   // [B,T,1]
    const float* weight    = (const float*)d_in[2];   // [B,T]
    const float* baselines = (const float*)d_in[3];   // [B,T,1]

    float* out = (float*)d_out;
    float* obj = out;            // [T]
    float* cum = out + TDIM;     // [B,T]

    // Prefer 4 rows/block (1024 blocks, 8 MB partial) for occupancy; fall back
    // to 8 rows/block (512 blocks, 4 MB) if workspace is tight.
    const size_t need1024 = ((size_t)1024 * TDIM + TDIM) * sizeof(float);
    const int rpb = (ws_size >= need1024) ? 4 : 8;
    const int k1_blocks = BDIM / rpb;

    float* partial = (float*)d_ws;                          // k1_blocks * 2048 floats
    float* colsum  = partial + (size_t)k1_blocks * TDIM;    // 2048 floats

    hipMemsetAsync(obj, 0, TDIM * sizeof(float), stream);
    hipMemsetAsync(colsum, 0, TDIM * sizeof(float), stream);

    k1_scan<<<k1_blocks, 256, 0, stream>>>(logits, weight, baselines, cum, partial, rpb);
    k2_colsum<<<256, 256, 0, stream>>>(partial, colsum, k1_blocks / 32);
    k3_obj<<<dim3(TDIM / (256 * 4), BDIM / K3_ROWS), 256, 0, stream>>>(
        cum, baselines, log_probs, colsum, obj);
}

// Round 3
// 181.749 us; speedup vs baseline: 1.1129x; 1.1129x over previous
//
#include <hip/hip_runtime.h>
#include <math.h>

// Problem constants (match reference).
#define BDIM 4096
#define TDIM 2048
#define NBLK 512          // k1 grid: BDIM / RPB
#define RPB  8            // rows per k1 block

// gamma powers as exact compile-time folded constants
constexpr double gpow(int e) {
    double r = 1.0;
    for (int i = 0; i < e; ++i) r *= 0.99;
    return r;
}

__device__ __forceinline__ float logsig_fast(float x) {
    // log(sigmoid(x)) = min(x,0) - log(1 + exp(-|x|))
    // __expf/__logf -> v_exp_f32/v_log_f32 (2 HW transcendentals instead of
    // ~20-op polynomial expf+log1pf). |err| ~1e-6 rel; threshold is 11.68 abs.
    float z = __expf(-fabsf(x));
    return fminf(x, 0.0f) - __logf(1.0f + z);
}

__device__ __forceinline__ float clip5(float x) {
    return fminf(fmaxf(x, -5.0f), 5.0f);
}

// ---------------------------------------------------------------------------
// K1: per-row reverse discounted scan (c[t] = wr[t] + g*c[t+1]); writes cum
// and per-block column partials. Block 0/1 zero colsum/obj (replaces memsets).
// ---------------------------------------------------------------------------
__global__ __launch_bounds__(256) void k1_scan(
    const float* __restrict__ logits,
    const float* __restrict__ weight,
    const float* __restrict__ baselines,
    float* __restrict__ cum_out,
    float* __restrict__ partial,
    float* __restrict__ colsum,
    float* __restrict__ obj)
{
    const int tid  = threadIdx.x;
    const int lane = tid & 63;
    const int wave = tid >> 6;
    const int t0   = tid * 8;          // 8 contiguous columns per thread

    // in-kernel zeroing: k2/k3 are stream-ordered after k1, so any k1 block
    // may do this at any time during k1.
    if (blockIdx.x == 0) {
        *reinterpret_cast<float4*>(colsum + t0)     = make_float4(0.f, 0.f, 0.f, 0.f);
        *reinterpret_cast<float4*>(colsum + t0 + 4) = make_float4(0.f, 0.f, 0.f, 0.f);
    }
    if (blockIdx.x == 1) {
        *reinterpret_cast<float4*>(obj + t0)     = make_float4(0.f, 0.f, 0.f, 0.f);
        *reinterpret_cast<float4*>(obj + t0 + 4) = make_float4(0.f, 0.f, 0.f, 0.f);
    }

    const float G    = 0.99f;
    const float G512 = (float)gpow(512);
    const float LOG2G = -0.014499569695115089f;  // log2(0.99)
    const float gk[8] = {(float)gpow(8), (float)gpow(7), (float)gpow(6), (float)gpow(5),
                         (float)gpow(4), (float)gpow(3), (float)gpow(2), (float)gpow(1)};
    // shuffle-scan factors G8^(2^s) as compile-time constants (no f*=f chain)
    const float fs[6] = {(float)gpow(8),  (float)gpow(16), (float)gpow(32),
                         (float)gpow(64), (float)gpow(128), (float)gpow(256)};
    const float lane_pow = exp2f((float)((64 - lane) * 8) * LOG2G);

    __shared__ float wsum[2][4];

    float colacc[8];
#pragma unroll
    for (int k = 0; k < 8; ++k) colacc[k] = 0.0f;

    const int row0 = blockIdx.x * RPB;
    size_t base = (size_t)row0 * TDIM + t0;

    // preload row 0
    float4 x0 = *reinterpret_cast<const float4*>(logits + base);
    float4 x1 = *reinterpret_cast<const float4*>(logits + base + 4);
    float4 w0 = *reinterpret_cast<const float4*>(weight + base);
    float4 w1 = *reinterpret_cast<const float4*>(weight + base + 4);
    float4 b0 = *reinterpret_cast<const float4*>(baselines + base);
    float4 b1 = *reinterpret_cast<const float4*>(baselines + base + 4);

    for (int r = 0; r < RPB; ++r) {
        const size_t nbase = base + TDIM;
        const bool has_next = (r + 1 < RPB);

        float wr[8];
        wr[0] = w0.x * logsig_fast(x0.x); wr[1] = w0.y * logsig_fast(x0.y);
        wr[2] = w0.z * logsig_fast(x0.z); wr[3] = w0.w * logsig_fast(x0.w);
        wr[4] = w1.x * logsig_fast(x1.x); wr[5] = w1.y * logsig_fast(x1.y);
        wr[6] = w1.z * logsig_fast(x1.z); wr[7] = w1.w * logsig_fast(x1.w);

        // prefetch next row: latency hides under the scan chain below
        float4 nx0, nx1, nw0, nw1, nb0, nb1;
        if (has_next) {
            nx0 = *reinterpret_cast<const float4*>(logits + nbase);
            nx1 = *reinterpret_cast<const float4*>(logits + nbase + 4);
            nw0 = *reinterpret_cast<const float4*>(weight + nbase);
            nw1 = *reinterpret_cast<const float4*>(weight + nbase + 4);
            nb0 = *reinterpret_cast<const float4*>(baselines + nbase);
            nb1 = *reinterpret_cast<const float4*>(baselines + nbase + 4);
        }

        // local suffix scan: loc[k] = sum_{s>=k} g^(s-k) wr[s]
        float loc[8];
        loc[7] = wr[7];
#pragma unroll
        for (int k = 6; k >= 0; --k) loc[k] = fmaf(G, loc[k + 1], wr[k]);

        // wave-level weighted suffix scan over per-thread totals
        float v = loc[0];
#pragma unroll
        for (int s = 0; s < 6; ++s) {
            const int o = 1 << s;
            float up = __shfl_down(v, (unsigned)o, 64);
            if (lane + o < 64) v = fmaf(fs[s], up, v);
        }

        // cross-wave carry via LDS — ONE barrier per row (double-buffered)
        const int buf = r & 1;
        if (lane == 0) wsum[buf][wave] = v;
        __syncthreads();
        const float W1 = wsum[buf][1], W2 = wsum[buf][2], W3 = wsum[buf][3];
        const float FC3 = W3;
        const float FC2 = fmaf(G512, FC3, W2);
        const float FC1 = fmaf(G512, FC2, W1);
        const float carry = (wave == 0) ? FC1 : (wave == 1) ? FC2 : (wave == 2) ? FC3 : 0.0f;

        const float vfull = fmaf(lane_pow, carry, v);
        const float vn = __shfl_down(vfull, 1, 64);
        const float tail = (lane == 63) ? carry : vn;

        float c[8];
#pragma unroll
        for (int k = 0; k < 8; ++k) c[k] = fmaf(gk[k], tail, loc[k]);

        *reinterpret_cast<float4*>(cum_out + base)     = make_float4(c[0], c[1], c[2], c[3]);
        *reinterpret_cast<float4*>(cum_out + base + 4) = make_float4(c[4], c[5], c[6], c[7]);

        colacc[0] += c[0] - b0.x; colacc[1] += c[1] - b0.y;
        colacc[2] += c[2] - b0.z; colacc[3] += c[3] - b0.w;
        colacc[4] += c[4] - b1.x; colacc[5] += c[5] - b1.y;
        colacc[6] += c[6] - b1.z; colacc[7] += c[7] - b1.w;

        base = nbase;
        if (has_next) {
            x0 = nx0; x1 = nx1; w0 = nw0; w1 = nw1; b0 = nb0; b1 = nb1;
        }
    }

    const size_t pbase = (size_t)blockIdx.x * TDIM + t0;
    *reinterpret_cast<float4*>(partial + pbase)     = make_float4(colacc[0], colacc[1], colacc[2], colacc[3]);
    *reinterpret_cast<float4*>(partial + pbase + 4) = make_float4(colacc[4], colacc[5], colacc[6], colacc[7]);
}

// ---------------------------------------------------------------------------
// K2: colsum[col] = sum over 512 partial rows (32 slices x 16 rows).
// ---------------------------------------------------------------------------
__global__ __launch_bounds__(256) void k2_colsum(
    const float* __restrict__ partial, float* __restrict__ colsum)
{
    const int gid = blockIdx.x * 256 + threadIdx.x;   // 0..65535
    const int col = gid & (TDIM - 1);
    const int slc = gid >> 11;                        // 0..31
    const float* p = partial + (size_t)slc * 16 * TDIM + col;
    float s = 0.0f;
#pragma unroll
    for (int i = 0; i < 16; ++i) s += p[(size_t)i * TDIM];
    atomicAdd(colsum + col, s);
}

// ---------------------------------------------------------------------------
// K3: obj[t] = sum_b clip(cum - baseline - mean, +-5) * log_probs.
// 32 rows/thread, 4 cols/thread (float4), 256 blocks, 128 atomics/col.
// ---------------------------------------------------------------------------
#define K3_ROWS 32
__global__ __launch_bounds__(256) void k3_obj(
    const float* __restrict__ cum,
    const float* __restrict__ baselines,
    const float* __restrict__ lp,
    const float* __restrict__ colsum,
    float* __restrict__ obj)
{
    const int c4 = (blockIdx.x * 256 + threadIdx.x) * 4;   // column group
    const int r0 = blockIdx.y * K3_ROWS;
    const float inv = 1.0f / (float)BDIM;
    float4 ms = *reinterpret_cast<const float4*>(colsum + c4);
    const float m0 = ms.x * inv, m1 = ms.y * inv, m2 = ms.z * inv, m3 = ms.w * inv;

    float a0 = 0.0f, a1 = 0.0f, a2 = 0.0f, a3 = 0.0f;
    size_t idx = (size_t)r0 * TDIM + c4;
#pragma unroll 8
    for (int r = 0; r < K3_ROWS; ++r, idx += TDIM) {
        float4 c = *reinterpret_cast<const float4*>(cum + idx);
        float4 b = *reinterpret_cast<const float4*>(baselines + idx);
        float4 l = *reinterpret_cast<const float4*>(lp + idx);
        a0 = fmaf(clip5(c.x - b.x - m0), l.x, a0);
        a1 = fmaf(clip5(c.y - b.y - m1), l.y, a1);
        a2 = fmaf(clip5(c.z - b.z - m2), l.z, a2);
        a3 = fmaf(clip5(c.w - b.w - m3), l.w, a3);
    }
    atomicAdd(obj + c4 + 0, a0);
    atomicAdd(obj + c4 + 1, a1);
    atomicAdd(obj + c4 + 2, a2);
    atomicAdd(obj + c4 + 3, a3);
}

extern "C" void kernel_launch(void* const* d_in, const int* in_sizes, int n_in,
                              void* d_out, int out_size, void* d_ws, size_t ws_size,
                              hipStream_t stream) {
    const float* log_probs = (const float*)d_in[0];   // [B,T]
    const float* logits    = (const float*)d_in[1];   // [B,T,1]
    const float* weight    = (const float*)d_in[2];   // [B,T]
    const float* baselines = (const float*)d_in[3];   // [B,T,1]

    float* out = (float*)d_out;
    float* obj = out;            // [T]
    float* cum = out + TDIM;     // [B,T]

    float* partial = (float*)d_ws;                       // NBLK*TDIM floats = 4 MB
    float* colsum  = partial + (size_t)NBLK * TDIM;      // 2048 floats

    k1_scan<<<NBLK, 256, 0, stream>>>(logits, weight, baselines, cum, partial, colsum, obj);
    k2_colsum<<<256, 256, 0, stream>>>(partial, colsum);
    k3_obj<<<dim3(TDIM / (256 * 4), BDIM / K3_ROWS), 256, 0, stream>>>(
        cum, baselines, log_probs, colsum, obj);
}